// Round 6
// baseline (959.631 us; speedup 1.0000x reference)
//
#include <hip/hip_runtime.h>
#include <math.h>

#define HDIM 512
#define NHEAD 8
#define NLAYER 6
#define SEQ 2048
#define BATCH 2
#define DHEAD 64
#define TOKENS (BATCH*SEQ)
#define FFND (4*HDIM)
#define QSTR 1536   // fused QKV row stride

typedef unsigned short u16;
typedef unsigned long long u64;
typedef __attribute__((ext_vector_type(8))) short short8;
typedef __attribute__((ext_vector_type(4))) float f32x4;

__device__ __forceinline__ u16 f2b(float f) {
  unsigned u = __float_as_uint(f);
  u += 0x7FFFu + ((u >> 16) & 1u);
  return (u16)(u >> 16);
}

__device__ __forceinline__ unsigned cvtpk_bf16(float lo, float hi) {
  unsigned r;
  asm("v_cvt_pk_bf16_f32 %0, %1, %2" : "=v"(r) : "v"(lo), "v"(hi));
  return r;
}

__device__ __forceinline__ void gload_lds16(const u16* g, u16* l) {
  __builtin_amdgcn_global_load_lds((const __attribute__((address_space(1))) void*)g,
                                   (__attribute__((address_space(3))) void*)l, 16, 0, 0);
}

// ---------------- embed + positional encoding ----------------
__global__ void embed_pe(const int* __restrict__ src, const float* __restrict__ emb,
                         float* __restrict__ X, u16* __restrict__ Xb) {
  int tok = blockIdx.x;
  int lane = threadIdx.x;           // 64 threads
  int s = tok & (SEQ - 1);
  int c0 = lane * 8;
  const float* e = emb + (long)src[tok] * HDIM + c0;
  float v[8];
#pragma unroll
  for (int j = 0; j < 8; j++) {
    int c = c0 + j;
    float arg = (float)s * exp2f(-(float)(c & ~1) * 0.02595256917f);
    v[j] = e[j] + ((c & 1) ? cosf(arg) : sinf(arg));
  }
  float* xp = X + (long)tok * HDIM + c0;
#pragma unroll
  for (int j = 0; j < 8; j++) xp[j] = v[j];
  u16 hb[8];
#pragma unroll
  for (int j = 0; j < 8; j++) hb[j] = f2b(v[j]);
  uint4 pk;
  pk.x = hb[0] | ((unsigned)hb[1] << 16);
  pk.y = hb[2] | ((unsigned)hb[3] << 16);
  pk.z = hb[4] | ((unsigned)hb[5] << 16);
  pk.w = hb[6] | ((unsigned)hb[7] << 16);
  *(uint4*)(Xb + (long)tok * HDIM + c0) = pk;
}

// ---------------- mask -> per-64-key-tile bitmasks (once per net) ----------------
__global__ void maskprep(const int* __restrict__ mask, u64* __restrict__ mb) {
  int t = threadIdx.x;              // 64 threads: b = t>>5, tile = t&31
  int b = t >> 5, tile = t & 31;
  const int* m = mask + b * SEQ + tile * 64;
  u64 w = 0;
#pragma unroll
  for (int j = 0; j < 64; j++) w |= (u64)(m[j] != 0) << j;
  mb[t] = w;
}

// ---------------- per-layer weight prep: fp32 [K][N] -> bf16 [N][K] ----------------
__global__ __launch_bounds__(256) void prep_weights(
    const float* __restrict__ Wq, const float* __restrict__ Wk, const float* __restrict__ Wv,
    const float* __restrict__ Wo, const float* __restrict__ W1, const float* __restrict__ W2,
    const float* __restrict__ bq, const float* __restrict__ bk, const float* __restrict__ bv,
    u16* __restrict__ Wqkvt, u16* __restrict__ Wot, u16* __restrict__ W1t, u16* __restrict__ W2t,
    float* __restrict__ bqkv) {
  int t = blockIdx.x;
  int tid = threadIdx.x;
  if (t == 768) {
    for (int i = tid; i < 1536; i += 256)
      bqkv[i] = (i < 512) ? bq[i] : (i < 1024) ? bk[i - 512] : bv[i - 1024];
    return;
  }
  const float* src; u16* dst; int K, N, kt, nt; long drow0 = 0;
  if (t < 192)      { int m = t / 64, r = t % 64; src = (m==0)?Wq:(m==1)?Wk:Wv; dst = Wqkvt; drow0 = (long)m*512; K=512;  N=512;  kt=r/8;  nt=r%8; }
  else if (t < 256) { int r = t - 192; src = Wo; dst = Wot; K=512;  N=512;  kt=r/8;  nt=r%8; }
  else if (t < 512) { int r = t - 256; src = W1; dst = W1t; K=512;  N=2048; kt=r/32; nt=r%32; }
  else              { int r = t - 512; src = W2; dst = W2t; K=2048; N=512;  kt=r/8;  nt=r%8; }
  __shared__ __align__(16) u16 Lt[64 * 72];
  int kl = tid >> 2;                 // local k row 0..63
#pragma unroll
  for (int rr = 0; rr < 4; rr++) {
    int cl = (tid & 3) * 4 + rr * 16;  // local n col
    float4 v = *(const float4*)(src + (long)(kt * 64 + kl) * N + nt * 64 + cl);
    Lt[(cl + 0) * 72 + kl] = f2b(v.x);
    Lt[(cl + 1) * 72 + kl] = f2b(v.y);
    Lt[(cl + 2) * 72 + kl] = f2b(v.z);
    Lt[(cl + 3) * 72 + kl] = f2b(v.w);
  }
  __syncthreads();
  int nl = tid >> 2;                 // out row (n) 0..63
  int kc = (tid & 3) * 16;           // out col chunk (k)
  u16* dp = dst + (drow0 + nt * 64 + nl) * (long)K + kt * 64 + kc;
  *(uint4*)dp       = *(const uint4*)&Lt[nl * 72 + kc];
  *(uint4*)(dp + 8) = *(const uint4*)&Lt[nl * 72 + kc + 8];
}

// ---------------- V transpose: QKV V-region -> Vtb[b][h][d][S] ----------------
__global__ __launch_bounds__(256) void vtranspose(const u16* __restrict__ QKV,
                                                  u16* __restrict__ Vtb) {
  __shared__ __align__(16) u16 Lt[64 * 72];
  int tid = threadIdx.x;
  int bh = blockIdx.y, b = bh >> 3, h = bh & 7;
  int s0 = blockIdx.x * 64;
  const u16* vsrc = QKV + (long)(b * SEQ + s0) * QSTR + 1024 + h * DHEAD;
  int key = tid >> 2, dc = (tid & 3) * 16;
  const u16* vp = vsrc + (long)key * QSTR + dc;
  uint4 v0 = *(const uint4*)vp;
  uint4 v1 = *(const uint4*)(vp + 8);
  unsigned vr[8] = { v0.x, v0.y, v0.z, v0.w, v1.x, v1.y, v1.z, v1.w };
#pragma unroll
  for (int j = 0; j < 8; j++) {
    Lt[(dc + 2 * j) * 72 + key]     = (u16)vr[j];
    Lt[(dc + 2 * j + 1) * 72 + key] = (u16)(vr[j] >> 16);
  }
  __syncthreads();
  int d = tid >> 2, kc = (tid & 3) * 16;
  u16* dst = Vtb + ((long)bh * DHEAD + d) * SEQ + s0 + kc;
  *(uint4*)dst       = *(const uint4*)&Lt[d * 72 + kc];
  *(uint4*)(dst + 8) = *(const uint4*)&Lt[d * 72 + kc + 8];
}

// ---------------- bf16 TN GEMM, double-buffered; BM in {128,64} ----------------
template <int BM, int BN, bool RELU, bool WF32, bool WB16>
__global__ __launch_bounds__(256) void gemm_tn(const u16* __restrict__ A,
                                               const u16* __restrict__ Bt,
                                               const float* __restrict__ bias,
                                               float* __restrict__ Cf,
                                               u16* __restrict__ Cb,
                                               int M, int N, int K) {
  constexpr int NF = BN / 32;                 // n-frags per wave
  constexpr int MF = BM / 32;                 // m-frags per wave
  __shared__ __align__(16) u16 As[2][BM * 32];
  __shared__ __align__(16) u16 Bs[2][BN * 32];
  int tid = threadIdx.x;
  int wave = tid >> 6, lane = tid & 63;
  int ln = lane & 15, hi = lane >> 4;
  int wm = wave >> 1, wn = wave & 1;
  int m0 = blockIdx.y * BM, n0 = blockIdx.x * BN;

  f32x4 acc[MF][NF] = {};

  int srow = lane >> 2;        // 0..15
  int skc  = (lane & 3) * 8;   // k-chunk within 32

  auto issue = [&](int kt, int buf) {
    int k0 = kt * 32;
#pragma unroll
    for (int j = 0; j < BM / 64; j++) {
      int row = (wave * (BM / 64) + j) * 16 + srow;
      gload_lds16(A + (long)(m0 + row) * K + k0 + skc, &As[buf][row * 32 + skc]);
    }
#pragma unroll
    for (int j = 0; j < BN / 64; j++) {
      int row = (wave * (BN / 64) + j) * 16 + srow;
      gload_lds16(Bt + (long)(n0 + row) * K + k0 + skc, &Bs[buf][row * 32 + skc]);
    }
  };

  int NT = K / 32;
  issue(0, 0);
  __syncthreads();
  for (int kt = 0; kt < NT; kt++) {
    int buf = kt & 1;
    if (kt + 1 < NT) issue(kt + 1, buf ^ 1);
    short8 af[MF], bf[NF];
#pragma unroll
    for (int mt = 0; mt < MF; mt++)
      af[mt] = *(const short8*)&As[buf][(wm * (BM / 2) + mt * 16 + ln) * 32 + 8 * hi];
#pragma unroll
    for (int nt = 0; nt < NF; nt++)
      bf[nt] = *(const short8*)&Bs[buf][(wn * (BN / 2) + nt * 16 + ln) * 32 + 8 * hi];
#pragma unroll
    for (int mt = 0; mt < MF; mt++)
#pragma unroll
      for (int nt = 0; nt < NF; nt++)
        acc[mt][nt] = __builtin_amdgcn_mfma_f32_16x16x32_bf16(af[mt], bf[nt], acc[mt][nt], 0, 0, 0);
    __syncthreads();
  }

#pragma unroll
  for (int mt = 0; mt < MF; mt++)
#pragma unroll
    for (int nt = 0; nt < NF; nt++)
#pragma unroll
      for (int r = 0; r < 4; r++) {
        int row = m0 + wm * (BM / 2) + mt * 16 + hi * 4 + r;
        int col = n0 + wn * (BN / 2) + nt * 16 + ln;
        float v = acc[mt][nt][r] + bias[col];
        if (RELU) v = fmaxf(v, 0.0f);
        if (WF32) Cf[(long)row * N + col] = v;
        if (WB16) Cb[(long)row * N + col] = f2b(v);
      }
}

// ---------------- flash attention, QBLK=128 (32 q/wave), key-split-4 ----------------
// Each wave processes 32 q-rows as two 16-q B-fragments against shared K/V
// fragments: every kf/vf ds_read feeds 2 MFMA -> LDS traffic halves (was the
// floor: 1GB -> 512MB).  Key-split-4 (kz in 0..3, 8 tiles each) keeps 1024
// blocks = 4 blocks/CU.  Register discipline: s[2][4] live only during QK,
// converted to D[2][4][2] (s freed) before PV; pb assembled per-ks in PV loop.
// Partials additive (no-max softmax); separate merge kernel (NO fences - R4).
__global__ __launch_bounds__(256) void attention(const u16* __restrict__ QKV,
                                                 const u16* __restrict__ Vtb,
                                                 const u64* __restrict__ maskb,
                                                 float* __restrict__ Opart,
                                                 float* __restrict__ Lpart) {
  __shared__ __align__(16) u16 Ks[2][64 * 64];  // [buf][slot][d]  (chunk-swizzled)
  __shared__ __align__(16) u16 Vs[2][64 * 64];  // [buf][d][key]   (chunk-swizzled)
  __shared__ u64 Msk[SEQ / 64];
  int tid = threadIdx.x, w = tid >> 6, lane = tid & 63;
  int ln = lane & 15, hi = lane >> 4;
  int h0 = hi & 1, h1 = hi >> 1, ln7 = ln & 7;
  int lin = blockIdx.x;                        // 1024 blocks, 1-D
  int lid = (lin & 7) * 128 + (lin >> 3);      // bijective XCD-contiguous swizzle
  int bh = lid >> 6, rem = lid & 63;
  int qt = rem >> 2, kz = rem & 3;
  int b = bh >> 3, h = bh & 7;
  int q0 = qt * 128 + w * 32;                  // wave's 32 q-rows
  const u16* qbase = QKV + (long)b * SEQ * QSTR + h * DHEAD;
  const u16* kbase = qbase + 512;
  const u16* vtbase = Vtb + (long)bh * DHEAD * SEQ;

  // Q fragments (B-operand): qf[qg][ks], lane holds Q[q0+qg*16+ln][ks*32+8*hi..]
  short8 qf[2][2];
#pragma unroll
  for (int qg = 0; qg < 2; qg++)
#pragma unroll
    for (int ks = 0; ks < 2; ks++)
      qf[qg][ks] = *(const short8*)(qbase + (long)(q0 + qg * 16 + ln) * QSTR + ks * 32 + 8 * hi);

  u64 mw0 = 0;
  if (tid < SEQ / 64) mw0 = maskb[b * (SEQ / 64) + tid];

  // staging geometry: 256 thr x 16B x 2 issues = 8KB per tile per buffer
  int sr0 = tid >> 3, sc = tid & 7;
  const u16 *kp0, *kp1, *vp0, *vp1;
  {
    int r1 = sr0 + 32;
    int key0 = (sr0 & 7) | ((sr0 & 0x18) << 1) | ((sr0 & 0x20) >> 2);
    int key1 = (r1 & 7) | ((r1 & 0x18) << 1) | ((r1 & 0x20) >> 2);
    kp0 = kbase + (long)key0 * QSTR + (sc ^ (sr0 & 7)) * 8;
    kp1 = kbase + (long)key1 * QSTR + (sc ^ (r1 & 7)) * 8;
    vp0 = vtbase + (long)sr0 * SEQ + (sc ^ (sr0 & 7)) * 8;
    vp1 = vtbase + (long)r1 * SEQ + (sc ^ (r1 & 7)) * 8;
  }
  int d0 = sr0 * 64 + sc * 8, d1 = d0 + 2048;

  auto issue = [&](int t, int buf) {
    long ko = (long)t * (64 * QSTR);
    int vo = t * 64;
    gload_lds16(kp0 + ko, &Ks[buf][d0]);
    gload_lds16(kp1 + ko, &Ks[buf][d1]);
    gload_lds16(vp0 + vo, &Vs[buf][d0]);
    gload_lds16(vp1 + vo, &Vs[buf][d1]);
  };

  f32x4 o[2][4] = {};
  float lsum[2] = {0.0f, 0.0f};
  const int t0 = kz * 8;
  const int NTL = 8;                           // tiles per block (key-split quarter)

  issue(t0, 0);
  issue(t0 + 1, 1);
  if (tid < SEQ / 64) Msk[tid] = mw0;
  asm volatile("s_waitcnt vmcnt(4)" ::: "memory");   // tile t0 (+q,+mask) done; t0+1 in flight
  __builtin_amdgcn_sched_barrier(0);
  __builtin_amdgcn_s_barrier();
  __builtin_amdgcn_sched_barrier(0);

  for (int ti = 0; ti < NTL; ti++) {
    int buf = ti & 1;
    u64 mw = Msk[t0 + ti];

    // S^T: s[qg][kb][r] = S[q=q0+qg*16+ln][slot = kb*16 + hi*4 + r]
    f32x4 s[2][4] = {};
    __builtin_amdgcn_s_setprio(1);
#pragma unroll
    for (int ks = 0; ks < 2; ks++)
#pragma unroll
      for (int kb = 0; kb < 4; kb++) {
        short8 kf = *(const short8*)&Ks[buf][(kb * 16 + ln) * 64 + (((ks << 2) + hi) ^ ln7) * 8];
        s[0][kb] = __builtin_amdgcn_mfma_f32_16x16x32_bf16(kf, qf[0][ks], s[0][kb], 0, 0, 0);
        s[1][kb] = __builtin_amdgcn_mfma_f32_16x16x32_bf16(kf, qf[1][ks], s[1][kb], 0, 0, 0);
      }
    __builtin_amdgcn_s_setprio(0);

    // softmax numerator + pack to bf16 pairs (s freed as D is built)
    unsigned D[2][4][2];
    if (mw == 0xFFFFFFFFFFFFFFFFull) {
#pragma unroll
      for (int qg = 0; qg < 2; qg++)
#pragma unroll
        for (int kb = 0; kb < 4; kb++) {
          float p[4];
#pragma unroll
          for (int r = 0; r < 4; r++) {
            float pv = __expf(s[qg][kb][r] * 0.125f);
            lsum[qg] += pv;
            p[r] = pv;
          }
          D[qg][kb][0] = cvtpk_bf16(p[0], p[1]);
          D[qg][kb][1] = cvtpk_bf16(p[2], p[3]);
        }
    } else {
      // lane's key bit positions: 16*h1 + 4*h0 + {0,32,8,40}[kb] + r (q-indep)
      unsigned shb = h1 * 16 + h0 * 4;
      u64 mws = mw >> shb;
      unsigned nib[4] = { (unsigned)mws & 0xFu, (unsigned)(mws >> 32) & 0xFu,
                          (unsigned)(mws >> 8) & 0xFu, (unsigned)(mws >> 40) & 0xFu };
#pragma unroll
      for (int qg = 0; qg < 2; qg++)
#pragma unroll
        for (int kb = 0; kb < 4; kb++) {
          float p[4];
#pragma unroll
          for (int r = 0; r < 4; r++) {
            float pv = __expf(s[qg][kb][r] * 0.125f);
            pv = ((nib[kb] >> r) & 1u) ? pv : 0.0f;
            lsum[qg] += pv;
            p[r] = pv;
          }
          D[qg][kb][0] = cvtpk_bf16(p[0], p[1]);
          D[qg][kb][1] = cvtpk_bf16(p[2], p[3]);
        }
    }

    // O^T += V^T @ P^T : pb assembled per-ks (keeps register peak low);
    // each vf read feeds both q-groups.
    __builtin_amdgcn_s_setprio(1);
#pragma unroll
    for (int ks = 0; ks < 2; ks++) {
      short8 pb[2];
#pragma unroll
      for (int qg = 0; qg < 2; qg++) {
        unsigned own0 = h0 ? D[qg][2 + ks][0] : D[qg][ks][0];
        unsigned own1 = h0 ? D[qg][2 + ks][1] : D[qg][ks][1];
        unsigned snd0 = h0 ? D[qg][ks][0] : D[qg][2 + ks][0];
        unsigned snd1 = h0 ? D[qg][ks][1] : D[qg][2 + ks][1];
        unsigned rc0 = (unsigned)__shfl_xor((int)snd0, 16);
        unsigned rc1 = (unsigned)__shfl_xor((int)snd1, 16);
        union { unsigned u[4]; short8 v; } pu;
        pu.u[0] = h0 ? rc0 : own0;
        pu.u[1] = h0 ? rc1 : own1;
        pu.u[2] = h0 ? own0 : rc0;
        pu.u[3] = h0 ? own1 : rc1;
        pb[qg] = pu.v;
      }
#pragma unroll
      for (int mb = 0; mb < 4; mb++) {
        short8 vf = *(const short8*)&Vs[buf][(mb * 16 + ln) * 64 + (((ks << 2) + hi) ^ ln7) * 8];
        o[0][mb] = __builtin_amdgcn_mfma_f32_16x16x32_bf16(vf, pb[0], o[0][mb], 0, 0, 0);
        o[1][mb] = __builtin_amdgcn_mfma_f32_16x16x32_bf16(vf, pb[1], o[1][mb], 0, 0, 0);
      }
    }
    __builtin_amdgcn_s_setprio(0);

    // barrier #1: all waves done READING buf (own ds reads drained first)
    asm volatile("s_waitcnt lgkmcnt(0)" ::: "memory");
    __builtin_amdgcn_sched_barrier(0);
    __builtin_amdgcn_s_barrier();
    __builtin_amdgcn_sched_barrier(0);
    // prefetch ti+2 into buf; wait only until ti+1's loads are home
    if (ti + 2 < NTL) {
      issue(t0 + ti + 2, buf);
      asm volatile("s_waitcnt vmcnt(4)" ::: "memory");
    } else {
      asm volatile("s_waitcnt vmcnt(0)" ::: "memory");
    }
    __builtin_amdgcn_sched_barrier(0);
    __builtin_amdgcn_s_barrier();   // barrier #2: tile ti+1 staged for everyone
    __builtin_amdgcn_sched_barrier(0);
  }

  // partial row-sums: combine over hi groups -> every lane has row total
#pragma unroll
  for (int qg = 0; qg < 2; qg++) {
    lsum[qg] += __shfl_xor(lsum[qg], 16);
    lsum[qg] += __shfl_xor(lsum[qg], 32);
  }

  // raw fp32 partial O: block-contiguous [128 q][64 d]
  float* OpB = Opart + (long)lid * 8192 + w * 2048;
#pragma unroll
  for (int qg = 0; qg < 2; qg++)
#pragma unroll
    for (int mb = 0; mb < 4; mb++)
      *(f32x4*)&OpB[(qg * 16 + ln) * 64 + mb * 16 + hi * 4] = o[qg][mb];
  if (hi == 0) {
    Lpart[(long)lid * 128 + w * 32 + ln]      = lsum[0];
    Lpart[(long)lid * 128 + w * 32 + 16 + ln] = lsum[1];
  }
}

// ---------------- merge key-split-4 partials -> bf16 AVb ----------------
__global__ __launch_bounds__(256) void attn_merge(const float* __restrict__ Op,
                                                  const float* __restrict__ Lp,
                                                  u16* __restrict__ Og) {
  int lin = blockIdx.x;                       // 256 blocks
  int mlid = (lin & 7) * 32 + (lin >> 3);     // XCD-matched swizzle (same L2 as producer)
  int bh = mlid >> 4, qt = mlid & 15;
  int b = bh >> 3, h = bh & 7;
  int tid = threadIdx.x;
  __shared__ float Ls[128];
  long lbase = (long)mlid * 4 * 128;          // producer lids = mlid*4 + kz
  if (tid < 128) {
    float l = Lp[lbase + tid] + Lp[lbase + 128 + tid] +
              Lp[lbase + 256 + tid] + Lp[lbase + 384 + tid];
    Ls[tid] = 1.0f / l;
  }
  __syncthreads();
  const float* P0 = Op + (long)mlid * 4 * 8192;
  u16* obase = Og + (long)b * SEQ * HDIM + (long)qt * 128 * HDIM + h * DHEAD;
#pragma unroll
  for (int j = 0; j < 8; j++) {
    int flat = j * 1024 + tid * 4;
    int row = flat >> 6, c = flat & 63;
    float4 a0 = *(const float4*)&P0[flat];
    float4 a1 = *(const float4*)&P0[8192 + flat];
    float4 a2 = *(const float4*)&P0[16384 + flat];
    float4 a3 = *(const float4*)&P0[24576 + flat];
    float rl = Ls[row];
    uint2 val;
    val.x = cvtpk_bf16((a0.x + a1.x + a2.x + a3.x) * rl, (a0.y + a1.y + a2.y + a3.y) * rl);
    val.y = cvtpk_bf16((a0.z + a1.z + a2.z + a3.z) * rl, (a0.w + a1.w + a2.w + a3.w) * rl);
    *(uint2*)(obase + (long)row * HDIM + c) = val;
  }
}

// ---------------- residual + LayerNorm over single fp32 sublayer output ----------------
__global__ __launch_bounds__(256) void ln_residual(const float* __restrict__ Xin,
                                                   const float* __restrict__ T0,
                                                   const float* __restrict__ gamma,
                                                   const float* __restrict__ beta,
                                                   float* __restrict__ Xout,
                                                   u16* __restrict__ Xb) {
  int tid = threadIdx.x, w = tid >> 6, lane = tid & 63;
  int row = blockIdx.x * 4 + w;
  const float* t0 = T0 + (long)row * HDIM;
  int c0 = lane * 8;
  float v[8];
  {
    float4 a0 = *(const float4*)(t0 + c0);
    float4 b0 = *(const float4*)(t0 + c0 + 4);
    v[0] = a0.x; v[1] = a0.y; v[2] = a0.z; v[3] = a0.w;
    v[4] = b0.x; v[5] = b0.y; v[6] = b0.z; v[7] = b0.w;
  }
  float sum = 0.0f;
#pragma unroll
  for (int j = 0; j < 8; j++) sum += v[j];
#pragma unroll
  for (int off = 32; off; off >>= 1) sum += __shfl_xor(sum, off);
  float mu = sum * (1.0f / HDIM);
  float sq = 0.0f;
#pragma unroll
  for (int j = 0; j < 8; j++) { float d = v[j] - mu; sq += d * d; }
#pragma unroll
  for (int off = 32; off; off >>= 1) sq += __shfl_xor(sq, off);
  float rs = rsqrtf(sq * (1.0f / HDIM) + 1e-5f);
  const float* xin = Xin + (long)row * HDIM + c0;
  float* xout = Xout + (long)row * HDIM + c0;
  u16 hb[8];
#pragma unroll
  for (int j = 0; j < 8; j++) {
    int c = c0 + j;
    float y = xin[j] + (v[j] - mu) * rs * gamma[c] + beta[c];
    xout[j] = y;
    hb[j] = f2b(y);
  }
  uint4 pk;
  pk.x = hb[0] | ((unsigned)hb[1] << 16);
  pk.y = hb[2] | ((unsigned)hb[3] << 16);
  pk.z = hb[4] | ((unsigned)hb[5] << 16);
  pk.w = hb[6] | ((unsigned)hb[7] << 16);
  *(uint4*)(Xb + (long)row * HDIM + c0) = pk;
}

// ---------------- launch ----------------
extern "C" void kernel_launch(void* const* d_in, const int* in_sizes, int n_in,
                              void* d_out, int out_size, void* d_ws, size_t ws_size,
                              hipStream_t stream) {
  const int*   src   = (const int*)d_in[0];
  const int*   mask  = (const int*)d_in[1];
  const float* emb   = (const float*)d_in[2];
  const float* Wq    = (const float*)d_in[3];
  const float* bq    = (const float*)d_in[4];
  const float* Wk    = (const float*)d_in[5];
  const float* bk    = (const float*)d_in[6];
  const float* Wv    = (const float*)d_in[7];
  const float* bv    = (const float*)d_in[8];
  const float* Wo    = (const float*)d_in[9];
  const float* bo    = (const float*)d_in[10];
  const float* gamma = (const float*)d_in[11];
  const float* beta  = (const float*)d_in[12];
  const float* W1    = (const float*)d_in[13];
  const float* b1    = (const float*)d_in[14];
  const float* W2    = (const float*)d_in[15];
  const float* b2    = (const float*)d_in[16];

  char* ws = (char*)d_ws;
  float* X     = (float*)(ws);                     // 0..8MB   fp32 residual
  u16*   Xb    = (u16*)(ws + (8ll << 20));         // 8..12MB  bf16 mirror
  u16*   QKVb  = (u16*)(ws + (12ll << 20));        // 12..24MB fused QKV bf16
  u16*   Mb    = (u16*)(ws + (12ll << 20));        // 12..28MB FFN mid (reuses QKV+AV)
  u16*   AVb   = (u16*)(ws + (24ll << 20));        // 24..28MB attn out bf16
  float* T     = (float*)(ws + (28ll << 20));      // 28..36MB fp32 sublayer output
  u16*   Wqkvt = (u16*)(ws + (44ll << 20));        // 1.5MB
  u16*   Wot   = (u16*)(ws + (45ll << 20) + (512ll << 10)); // 0.5MB
  u16*   W1t   = (u16*)(ws + (46ll << 20));        // 2MB
  u16*   W2t   = (u16*)(ws + (48ll << 20));        // 2MB
  float* bqkv  = (float*)(ws + (50ll << 20));      // 6KB
  float* Lpart = (float*)(ws + (50ll << 20) + (512ll << 10)); // 512KB attn lsum partials
  u16*   Vtb   = (u16*)(ws + (51ll << 20));        // 4MB V^T [b][h][d][S]
  u64*   maskbits = (u64*)(ws + (55ll << 20));     // 512B per-tile mask bitmasks
  float* Opart = (float*)(ws + (56ll << 20));      // 56..88MB attn fp32 O partials

  embed_pe<<<dim3(TOKENS), dim3(64), 0, stream>>>(src, emb, X, Xb);
  maskprep<<<dim3(1), dim3(64), 0, stream>>>(mask, maskbits);

  for (int i = 0; i < NLAYER; i++) {
    long wo = (long)i * HDIM * HDIM;
    prep_weights<<<dim3(769), 256, 0, stream>>>(
        Wq + wo, Wk + wo, Wv + wo, Wo + wo,
        W1 + (long)i * HDIM * FFND, W2 + (long)i * FFND * HDIM,
        bq + i * HDIM, bk + i * HDIM, bv + i * HDIM,
        Wqkvt, Wot, W1t, W2t, bqkv);

    gemm_tn<128, 128, false, false, true><<<dim3(QSTR / 128, TOKENS / 128), 256, 0, stream>>>(
        Xb, Wqkvt, bqkv, nullptr, QKVb, TOKENS, QSTR, HDIM);

    vtranspose<<<dim3(SEQ / 64, BATCH * NHEAD), 256, 0, stream>>>(QKVb, Vtb);

    attention<<<dim3(1024), 256, 0, stream>>>(QKVb, Vtb, maskbits, Opart, Lpart);

    attn_merge<<<dim3(256), 256, 0, stream>>>(Opart, Lpart, AVb);

    gemm_tn<64, 64, false, true, false><<<dim3(HDIM / 64, TOKENS / 64), 256, 0, stream>>>(
        AVb, Wot, bo + i * HDIM, T, nullptr, TOKENS, HDIM, HDIM);

    ln_residual<<<dim3(TOKENS / 4), 256, 0, stream>>>(X, T, gamma + i * HDIM,
                                                      beta + i * HDIM, X, Xb);

    gemm_tn<128, 128, true, false, true><<<dim3(FFND / 128, TOKENS / 128), 256, 0, stream>>>(
        Xb, W1t, b1 + (long)i * FFND, nullptr, Mb, TOKENS, FFND, HDIM);

    gemm_tn<64, 64, false, true, false><<<dim3(HDIM / 64, TOKENS / 64), 256, 0, stream>>>(
        Mb, W2t, b2 + i * HDIM, T, nullptr, TOKENS, HDIM, FFND);

    ln_residual<<<dim3(TOKENS / 4), 256, 0, stream>>>(X, T, gamma + i * HDIM,
                                                      beta + i * HDIM, X, Xb);
  }

  hipMemcpyAsync(d_out, X, (size_t)TOKENS * HDIM * sizeof(float),
                 hipMemcpyDeviceToDevice, stream);
}

// Round 7
// 916.176 us; speedup vs baseline: 1.0474x; 1.0474x over previous
//
#include <hip/hip_runtime.h>
#include <math.h>

#define HDIM 512
#define NHEAD 8
#define NLAYER 6
#define SEQ 2048
#define BATCH 2
#define DHEAD 64
#define TOKENS (BATCH*SEQ)
#define FFND (4*HDIM)
#define QSTR 1536   // fused QKV row stride

typedef unsigned short u16;
typedef unsigned long long u64;
typedef __attribute__((ext_vector_type(8))) short short8;
typedef __attribute__((ext_vector_type(4))) float f32x4;

__device__ __forceinline__ u16 f2b(float f) {
  unsigned u = __float_as_uint(f);
  u += 0x7FFFu + ((u >> 16) & 1u);
  return (u16)(u >> 16);
}

__device__ __forceinline__ float b2f(u16 u) {
  return __uint_as_float((unsigned)u << 16);
}

__device__ __forceinline__ unsigned cvtpk_bf16(float lo, float hi) {
  unsigned r;
  asm("v_cvt_pk_bf16_f32 %0, %1, %2" : "=v"(r) : "v"(lo), "v"(hi));
  return r;
}

__device__ __forceinline__ void gload_lds16(const u16* g, u16* l) {
  __builtin_amdgcn_global_load_lds((const __attribute__((address_space(1))) void*)g,
                                   (__attribute__((address_space(3))) void*)l, 16, 0, 0);
}

// ---------------- embed + positional encoding ----------------
__global__ void embed_pe(const int* __restrict__ src, const float* __restrict__ emb,
                         float* __restrict__ X, u16* __restrict__ Xb) {
  int tok = blockIdx.x;
  int lane = threadIdx.x;           // 64 threads
  int s = tok & (SEQ - 1);
  int c0 = lane * 8;
  const float* e = emb + (long)src[tok] * HDIM + c0;
  float v[8];
#pragma unroll
  for (int j = 0; j < 8; j++) {
    int c = c0 + j;
    float arg = (float)s * exp2f(-(float)(c & ~1) * 0.02595256917f);
    v[j] = e[j] + ((c & 1) ? cosf(arg) : sinf(arg));
  }
  float* xp = X + (long)tok * HDIM + c0;
#pragma unroll
  for (int j = 0; j < 8; j++) xp[j] = v[j];
  u16 hb[8];
#pragma unroll
  for (int j = 0; j < 8; j++) hb[j] = f2b(v[j]);
  uint4 pk;
  pk.x = hb[0] | ((unsigned)hb[1] << 16);
  pk.y = hb[2] | ((unsigned)hb[3] << 16);
  pk.z = hb[4] | ((unsigned)hb[5] << 16);
  pk.w = hb[6] | ((unsigned)hb[7] << 16);
  *(uint4*)(Xb + (long)tok * HDIM + c0) = pk;
}

// ---------------- mask -> per-64-key-tile bitmasks (once per net) ----------------
__global__ void maskprep(const int* __restrict__ mask, u64* __restrict__ mb) {
  int t = threadIdx.x;              // 64 threads: b = t>>5, tile = t&31
  int b = t >> 5, tile = t & 31;
  const int* m = mask + b * SEQ + tile * 64;
  u64 w = 0;
#pragma unroll
  for (int j = 0; j < 64; j++) w |= (u64)(m[j] != 0) << j;
  mb[t] = w;
}

// ---------------- ALL-layer weight prep (once): fp32 [K][N] -> bf16 [N][K] ----------------
// grid (769, NLAYER); weights are loop-invariant so this runs once, off the
// per-layer critical path (was 6 serialized ~5us dispatches).
__global__ __launch_bounds__(256) void prep_weights(
    const float* __restrict__ Wq, const float* __restrict__ Wk, const float* __restrict__ Wv,
    const float* __restrict__ Wo, const float* __restrict__ W1, const float* __restrict__ W2,
    const float* __restrict__ bq, const float* __restrict__ bk, const float* __restrict__ bv,
    u16* __restrict__ Wqkvt, u16* __restrict__ Wot, u16* __restrict__ W1t, u16* __restrict__ W2t,
    float* __restrict__ bqkv) {
  int L = blockIdx.y;
  int t = blockIdx.x;
  int tid = threadIdx.x;
  const float* Wq_ = Wq + (long)L * HDIM * HDIM;
  const float* Wk_ = Wk + (long)L * HDIM * HDIM;
  const float* Wv_ = Wv + (long)L * HDIM * HDIM;
  const float* Wo_ = Wo + (long)L * HDIM * HDIM;
  const float* W1_ = W1 + (long)L * HDIM * FFND;
  const float* W2_ = W2 + (long)L * FFND * HDIM;
  u16* Wqkvt_ = Wqkvt + (long)L * QSTR * HDIM;
  u16* Wot_   = Wot   + (long)L * HDIM * HDIM;
  u16* W1t_   = W1t   + (long)L * HDIM * FFND;
  u16* W2t_   = W2t   + (long)L * FFND * HDIM;
  if (t == 768) {
    const float* bq_ = bq + L * HDIM;
    const float* bk_ = bk + L * HDIM;
    const float* bv_ = bv + L * HDIM;
    float* bqkv_ = bqkv + L * QSTR;
    for (int i = tid; i < 1536; i += 256)
      bqkv_[i] = (i < 512) ? bq_[i] : (i < 1024) ? bk_[i - 512] : bv_[i - 1024];
    return;
  }
  const float* src; u16* dst; int K, N, kt, nt; long drow0 = 0;
  if (t < 192)      { int m = t / 64, r = t % 64; src = (m==0)?Wq_:(m==1)?Wk_:Wv_; dst = Wqkvt_; drow0 = (long)m*512; K=512;  N=512;  kt=r/8;  nt=r%8; }
  else if (t < 256) { int r = t - 192; src = Wo_; dst = Wot_; K=512;  N=512;  kt=r/8;  nt=r%8; }
  else if (t < 512) { int r = t - 256; src = W1_; dst = W1t_; K=512;  N=2048; kt=r/32; nt=r%32; }
  else              { int r = t - 512; src = W2_; dst = W2t_; K=2048; N=512;  kt=r/8;  nt=r%8; }
  __shared__ __align__(16) u16 Lt[64 * 72];
  int kl = tid >> 2;                 // local k row 0..63
#pragma unroll
  for (int rr = 0; rr < 4; rr++) {
    int cl = (tid & 3) * 4 + rr * 16;  // local n col
    float4 v = *(const float4*)(src + (long)(kt * 64 + kl) * N + nt * 64 + cl);
    Lt[(cl + 0) * 72 + kl] = f2b(v.x);
    Lt[(cl + 1) * 72 + kl] = f2b(v.y);
    Lt[(cl + 2) * 72 + kl] = f2b(v.z);
    Lt[(cl + 3) * 72 + kl] = f2b(v.w);
  }
  __syncthreads();
  int nl = tid >> 2;                 // out row (n) 0..63
  int kc = (tid & 3) * 16;           // out col chunk (k)
  u16* dp = dst + (drow0 + nt * 64 + nl) * (long)K + kt * 64 + kc;
  *(uint4*)dp       = *(const uint4*)&Lt[nl * 72 + kc];
  *(uint4*)(dp + 8) = *(const uint4*)&Lt[nl * 72 + kc + 8];
}

// ---------------- V transpose: QKV V-region -> Vtb[b][h][d][S] ----------------
__global__ __launch_bounds__(256) void vtranspose(const u16* __restrict__ QKV,
                                                  u16* __restrict__ Vtb) {
  __shared__ __align__(16) u16 Lt[64 * 72];
  int tid = threadIdx.x;
  int bh = blockIdx.y, b = bh >> 3, h = bh & 7;
  int s0 = blockIdx.x * 64;
  const u16* vsrc = QKV + (long)(b * SEQ + s0) * QSTR + 1024 + h * DHEAD;
  int key = tid >> 2, dc = (tid & 3) * 16;
  const u16* vp = vsrc + (long)key * QSTR + dc;
  uint4 v0 = *(const uint4*)vp;
  uint4 v1 = *(const uint4*)(vp + 8);
  unsigned vr[8] = { v0.x, v0.y, v0.z, v0.w, v1.x, v1.y, v1.z, v1.w };
#pragma unroll
  for (int j = 0; j < 8; j++) {
    Lt[(dc + 2 * j) * 72 + key]     = (u16)vr[j];
    Lt[(dc + 2 * j + 1) * 72 + key] = (u16)(vr[j] >> 16);
  }
  __syncthreads();
  int d = tid >> 2, kc = (tid & 3) * 16;
  u16* dst = Vtb + ((long)bh * DHEAD + d) * SEQ + s0 + kc;
  *(uint4*)dst       = *(const uint4*)&Lt[d * 72 + kc];
  *(uint4*)(dst + 8) = *(const uint4*)&Lt[d * 72 + kc + 8];
}

// ---------------- bf16 TN GEMM, double-buffered; BM in {128,64} ----------------
template <int BM, int BN, bool RELU, bool WF32, bool WB16>
__global__ __launch_bounds__(256) void gemm_tn(const u16* __restrict__ A,
                                               const u16* __restrict__ Bt,
                                               const float* __restrict__ bias,
                                               float* __restrict__ Cf,
                                               u16* __restrict__ Cb,
                                               int M, int N, int K) {
  constexpr int NF = BN / 32;                 // n-frags per wave
  constexpr int MF = BM / 32;                 // m-frags per wave
  __shared__ __align__(16) u16 As[2][BM * 32];
  __shared__ __align__(16) u16 Bs[2][BN * 32];
  int tid = threadIdx.x;
  int wave = tid >> 6, lane = tid & 63;
  int ln = lane & 15, hi = lane >> 4;
  int wm = wave >> 1, wn = wave & 1;
  int m0 = blockIdx.y * BM, n0 = blockIdx.x * BN;

  f32x4 acc[MF][NF] = {};

  int srow = lane >> 2;        // 0..15
  int skc  = (lane & 3) * 8;   // k-chunk within 32

  auto issue = [&](int kt, int buf) {
    int k0 = kt * 32;
#pragma unroll
    for (int j = 0; j < BM / 64; j++) {
      int row = (wave * (BM / 64) + j) * 16 + srow;
      gload_lds16(A + (long)(m0 + row) * K + k0 + skc, &As[buf][row * 32 + skc]);
    }
#pragma unroll
    for (int j = 0; j < BN / 64; j++) {
      int row = (wave * (BN / 64) + j) * 16 + srow;
      gload_lds16(Bt + (long)(n0 + row) * K + k0 + skc, &Bs[buf][row * 32 + skc]);
    }
  };

  int NT = K / 32;
  issue(0, 0);
  __syncthreads();
  for (int kt = 0; kt < NT; kt++) {
    int buf = kt & 1;
    if (kt + 1 < NT) issue(kt + 1, buf ^ 1);
    short8 af[MF], bf[NF];
#pragma unroll
    for (int mt = 0; mt < MF; mt++)
      af[mt] = *(const short8*)&As[buf][(wm * (BM / 2) + mt * 16 + ln) * 32 + 8 * hi];
#pragma unroll
    for (int nt = 0; nt < NF; nt++)
      bf[nt] = *(const short8*)&Bs[buf][(wn * (BN / 2) + nt * 16 + ln) * 32 + 8 * hi];
#pragma unroll
    for (int mt = 0; mt < MF; mt++)
#pragma unroll
      for (int nt = 0; nt < NF; nt++)
        acc[mt][nt] = __builtin_amdgcn_mfma_f32_16x16x32_bf16(af[mt], bf[nt], acc[mt][nt], 0, 0, 0);
    __syncthreads();
  }

#pragma unroll
  for (int mt = 0; mt < MF; mt++)
#pragma unroll
    for (int nt = 0; nt < NF; nt++)
#pragma unroll
      for (int r = 0; r < 4; r++) {
        int row = m0 + wm * (BM / 2) + mt * 16 + hi * 4 + r;
        int col = n0 + wn * (BN / 2) + nt * 16 + ln;
        float v = acc[mt][nt][r] + bias[col];
        if (RELU) v = fmaxf(v, 0.0f);
        if (WF32) Cf[(long)row * N + col] = v;
        if (WB16) Cb[(long)row * N + col] = f2b(v);
      }
}

// ---------------- flash attention, QBLK=128 (32 q/wave), key-split-4, bf16 partials ----------------
// R6 structure (shared K/V fragments feed 2 MFMA each -> LDS traffic halved;
// key-split-4 keeps 4 blocks/CU) but partial O stored as BF16 not fp32:
// partials are pre-division sums, bf16 rounding adds <0.5% relative before the
// final (l0+..+l3) division -> halves the partial HBM/L2 round-trip that caused
// R6's regression.  Separate merge kernel (NO fences - R4 lesson).
__global__ __launch_bounds__(256) void attention(const u16* __restrict__ QKV,
                                                 const u16* __restrict__ Vtb,
                                                 const u64* __restrict__ maskb,
                                                 u16* __restrict__ Opart,
                                                 float* __restrict__ Lpart) {
  __shared__ __align__(16) u16 Ks[2][64 * 64];  // [buf][slot][d]  (chunk-swizzled)
  __shared__ __align__(16) u16 Vs[2][64 * 64];  // [buf][d][key]   (chunk-swizzled)
  __shared__ u64 Msk[SEQ / 64];
  int tid = threadIdx.x, w = tid >> 6, lane = tid & 63;
  int ln = lane & 15, hi = lane >> 4;
  int h0 = hi & 1, h1 = hi >> 1, ln7 = ln & 7;
  int lin = blockIdx.x;                        // 1024 blocks, 1-D
  int lid = (lin & 7) * 128 + (lin >> 3);      // bijective XCD-contiguous swizzle
  int bh = lid >> 6, rem = lid & 63;
  int qt = rem >> 2, kz = rem & 3;
  int b = bh >> 3, h = bh & 7;
  int q0 = qt * 128 + w * 32;                  // wave's 32 q-rows
  const u16* qbase = QKV + (long)b * SEQ * QSTR + h * DHEAD;
  const u16* kbase = qbase + 512;
  const u16* vtbase = Vtb + (long)bh * DHEAD * SEQ;

  // Q fragments (B-operand): qf[qg][ks], lane holds Q[q0+qg*16+ln][ks*32+8*hi..]
  short8 qf[2][2];
#pragma unroll
  for (int qg = 0; qg < 2; qg++)
#pragma unroll
    for (int ks = 0; ks < 2; ks++)
      qf[qg][ks] = *(const short8*)(qbase + (long)(q0 + qg * 16 + ln) * QSTR + ks * 32 + 8 * hi);

  u64 mw0 = 0;
  if (tid < SEQ / 64) mw0 = maskb[b * (SEQ / 64) + tid];

  // staging geometry: 256 thr x 16B x 2 issues = 8KB per tile per buffer
  int sr0 = tid >> 3, sc = tid & 7;
  const u16 *kp0, *kp1, *vp0, *vp1;
  {
    int r1 = sr0 + 32;
    int key0 = (sr0 & 7) | ((sr0 & 0x18) << 1) | ((sr0 & 0x20) >> 2);
    int key1 = (r1 & 7) | ((r1 & 0x18) << 1) | ((r1 & 0x20) >> 2);
    kp0 = kbase + (long)key0 * QSTR + (sc ^ (sr0 & 7)) * 8;
    kp1 = kbase + (long)key1 * QSTR + (sc ^ (r1 & 7)) * 8;
    vp0 = vtbase + (long)sr0 * SEQ + (sc ^ (sr0 & 7)) * 8;
    vp1 = vtbase + (long)r1 * SEQ + (sc ^ (r1 & 7)) * 8;
  }
  int d0 = sr0 * 64 + sc * 8, d1 = d0 + 2048;

  auto issue = [&](int t, int buf) {
    long ko = (long)t * (64 * QSTR);
    int vo = t * 64;
    gload_lds16(kp0 + ko, &Ks[buf][d0]);
    gload_lds16(kp1 + ko, &Ks[buf][d1]);
    gload_lds16(vp0 + vo, &Vs[buf][d0]);
    gload_lds16(vp1 + vo, &Vs[buf][d1]);
  };

  f32x4 o[2][4] = {};
  float lsum[2] = {0.0f, 0.0f};
  const int t0 = kz * 8;
  const int NTL = 8;                           // tiles per block (key-split quarter)

  issue(t0, 0);
  issue(t0 + 1, 1);
  if (tid < SEQ / 64) Msk[tid] = mw0;
  asm volatile("s_waitcnt vmcnt(4)" ::: "memory");   // tile t0 (+q,+mask) done; t0+1 in flight
  __builtin_amdgcn_sched_barrier(0);
  __builtin_amdgcn_s_barrier();
  __builtin_amdgcn_sched_barrier(0);

  for (int ti = 0; ti < NTL; ti++) {
    int buf = ti & 1;
    u64 mw = Msk[t0 + ti];

    // S^T: s[qg][kb][r] = S[q=q0+qg*16+ln][slot = kb*16 + hi*4 + r]
    f32x4 s[2][4] = {};
    __builtin_amdgcn_s_setprio(1);
#pragma unroll
    for (int ks = 0; ks < 2; ks++)
#pragma unroll
      for (int kb = 0; kb < 4; kb++) {
        short8 kf = *(const short8*)&Ks[buf][(kb * 16 + ln) * 64 + (((ks << 2) + hi) ^ ln7) * 8];
        s[0][kb] = __builtin_amdgcn_mfma_f32_16x16x32_bf16(kf, qf[0][ks], s[0][kb], 0, 0, 0);
        s[1][kb] = __builtin_amdgcn_mfma_f32_16x16x32_bf16(kf, qf[1][ks], s[1][kb], 0, 0, 0);
      }
    __builtin_amdgcn_s_setprio(0);

    // softmax numerator + pack to bf16 pairs (s freed as D is built)
    unsigned D[2][4][2];
    if (mw == 0xFFFFFFFFFFFFFFFFull) {
#pragma unroll
      for (int qg = 0; qg < 2; qg++)
#pragma unroll
        for (int kb = 0; kb < 4; kb++) {
          float p[4];
#pragma unroll
          for (int r = 0; r < 4; r++) {
            float pv = __expf(s[qg][kb][r] * 0.125f);
            lsum[qg] += pv;
            p[r] = pv;
          }
          D[qg][kb][0] = cvtpk_bf16(p[0], p[1]);
          D[qg][kb][1] = cvtpk_bf16(p[2], p[3]);
        }
    } else {
      // lane's key bit positions: 16*h1 + 4*h0 + {0,32,8,40}[kb] + r (q-indep)
      unsigned shb = h1 * 16 + h0 * 4;
      u64 mws = mw >> shb;
      unsigned nib[4] = { (unsigned)mws & 0xFu, (unsigned)(mws >> 32) & 0xFu,
                          (unsigned)(mws >> 8) & 0xFu, (unsigned)(mws >> 40) & 0xFu };
#pragma unroll
      for (int qg = 0; qg < 2; qg++)
#pragma unroll
        for (int kb = 0; kb < 4; kb++) {
          float p[4];
#pragma unroll
          for (int r = 0; r < 4; r++) {
            float pv = __expf(s[qg][kb][r] * 0.125f);
            pv = ((nib[kb] >> r) & 1u) ? pv : 0.0f;
            lsum[qg] += pv;
            p[r] = pv;
          }
          D[qg][kb][0] = cvtpk_bf16(p[0], p[1]);
          D[qg][kb][1] = cvtpk_bf16(p[2], p[3]);
        }
    }

    // O^T += V^T @ P^T : pb assembled per-ks (keeps register peak low);
    // each vf read feeds both q-groups.
    __builtin_amdgcn_s_setprio(1);
#pragma unroll
    for (int ks = 0; ks < 2; ks++) {
      short8 pb[2];
#pragma unroll
      for (int qg = 0; qg < 2; qg++) {
        unsigned own0 = h0 ? D[qg][2 + ks][0] : D[qg][ks][0];
        unsigned own1 = h0 ? D[qg][2 + ks][1] : D[qg][ks][1];
        unsigned snd0 = h0 ? D[qg][ks][0] : D[qg][2 + ks][0];
        unsigned snd1 = h0 ? D[qg][ks][1] : D[qg][2 + ks][1];
        unsigned rc0 = (unsigned)__shfl_xor((int)snd0, 16);
        unsigned rc1 = (unsigned)__shfl_xor((int)snd1, 16);
        union { unsigned u[4]; short8 v; } pu;
        pu.u[0] = h0 ? rc0 : own0;
        pu.u[1] = h0 ? rc1 : own1;
        pu.u[2] = h0 ? own0 : rc0;
        pu.u[3] = h0 ? own1 : rc1;
        pb[qg] = pu.v;
      }
#pragma unroll
      for (int mb = 0; mb < 4; mb++) {
        short8 vf = *(const short8*)&Vs[buf][(mb * 16 + ln) * 64 + (((ks << 2) + hi) ^ ln7) * 8];
        o[0][mb] = __builtin_amdgcn_mfma_f32_16x16x32_bf16(vf, pb[0], o[0][mb], 0, 0, 0);
        o[1][mb] = __builtin_amdgcn_mfma_f32_16x16x32_bf16(vf, pb[1], o[1][mb], 0, 0, 0);
      }
    }
    __builtin_amdgcn_s_setprio(0);

    // barrier #1: all waves done READING buf (own ds reads drained first)
    asm volatile("s_waitcnt lgkmcnt(0)" ::: "memory");
    __builtin_amdgcn_sched_barrier(0);
    __builtin_amdgcn_s_barrier();
    __builtin_amdgcn_sched_barrier(0);
    // prefetch ti+2 into buf; wait only until ti+1's loads are home
    if (ti + 2 < NTL) {
      issue(t0 + ti + 2, buf);
      asm volatile("s_waitcnt vmcnt(4)" ::: "memory");
    } else {
      asm volatile("s_waitcnt vmcnt(0)" ::: "memory");
    }
    __builtin_amdgcn_sched_barrier(0);
    __builtin_amdgcn_s_barrier();   // barrier #2: tile ti+1 staged for everyone
    __builtin_amdgcn_sched_barrier(0);
  }

  // partial row-sums: combine over hi groups -> every lane has row total
#pragma unroll
  for (int qg = 0; qg < 2; qg++) {
    lsum[qg] += __shfl_xor(lsum[qg], 16);
    lsum[qg] += __shfl_xor(lsum[qg], 32);
  }

  // bf16 partial O: block-contiguous [128 q][64 d]
  u16* OpB = Opart + (long)lid * 8192 + w * 2048;
#pragma unroll
  for (int qg = 0; qg < 2; qg++)
#pragma unroll
    for (int mb = 0; mb < 4; mb++) {
      uint2 val;
      val.x = cvtpk_bf16(o[qg][mb][0], o[qg][mb][1]);
      val.y = cvtpk_bf16(o[qg][mb][2], o[qg][mb][3]);
      *(uint2*)&OpB[(qg * 16 + ln) * 64 + mb * 16 + hi * 4] = val;
    }
  if (hi == 0) {
    Lpart[(long)lid * 128 + w * 32 + ln]      = lsum[0];
    Lpart[(long)lid * 128 + w * 32 + 16 + ln] = lsum[1];
  }
}

// ---------------- merge key-split-4 bf16 partials -> bf16 AVb ----------------
__global__ __launch_bounds__(256) void attn_merge(const u16* __restrict__ Op,
                                                  const float* __restrict__ Lp,
                                                  u16* __restrict__ Og) {
  int lin = blockIdx.x;                       // 256 blocks
  int mlid = (lin & 7) * 32 + (lin >> 3);     // XCD-matched swizzle (same L2 as producer)
  int bh = mlid >> 4, qt = mlid & 15;
  int b = bh >> 3, h = bh & 7;
  int tid = threadIdx.x;
  __shared__ float Ls[128];
  long lbase = (long)mlid * 4 * 128;          // producer lids = mlid*4 + kz
  if (tid < 128) {
    float l = Lp[lbase + tid] + Lp[lbase + 128 + tid] +
              Lp[lbase + 256 + tid] + Lp[lbase + 384 + tid];
    Ls[tid] = 1.0f / l;
  }
  __syncthreads();
  const u16* P0 = Op + (long)mlid * 4 * 8192;
  u16* obase = Og + (long)b * SEQ * HDIM + (long)qt * 128 * HDIM + h * DHEAD;
#pragma unroll
  for (int j = 0; j < 8; j++) {
    int flat = j * 1024 + tid * 4;
    int row = flat >> 6, c = flat & 63;
    float a0 = 0.0f, a1 = 0.0f, a2 = 0.0f, a3 = 0.0f;
#pragma unroll
    for (int z = 0; z < 4; z++) {
      uint2 pv = *(const uint2*)&P0[z * 8192 + flat];
      a0 += b2f((u16)pv.x);  a1 += b2f((u16)(pv.x >> 16));
      a2 += b2f((u16)pv.y);  a3 += b2f((u16)(pv.y >> 16));
    }
    float rl = Ls[row];
    uint2 val;
    val.x = cvtpk_bf16(a0 * rl, a1 * rl);
    val.y = cvtpk_bf16(a2 * rl, a3 * rl);
    *(uint2*)(obase + (long)row * HDIM + c) = val;
  }
}

// ---------------- residual + LayerNorm over single fp32 sublayer output ----------------
__global__ __launch_bounds__(256) void ln_residual(const float* __restrict__ Xin,
                                                   const float* __restrict__ T0,
                                                   const float* __restrict__ gamma,
                                                   const float* __restrict__ beta,
                                                   float* __restrict__ Xout,
                                                   u16* __restrict__ Xb) {
  int tid = threadIdx.x, w = tid >> 6, lane = tid & 63;
  int row = blockIdx.x * 4 + w;
  const float* t0 = T0 + (long)row * HDIM;
  int c0 = lane * 8;
  float v[8];
  {
    float4 a0 = *(const float4*)(t0 + c0);
    float4 b0 = *(const float4*)(t0 + c0 + 4);
    v[0] = a0.x; v[1] = a0.y; v[2] = a0.z; v[3] = a0.w;
    v[4] = b0.x; v[5] = b0.y; v[6] = b0.z; v[7] = b0.w;
  }
  float sum = 0.0f;
#pragma unroll
  for (int j = 0; j < 8; j++) sum += v[j];
#pragma unroll
  for (int off = 32; off; off >>= 1) sum += __shfl_xor(sum, off);
  float mu = sum * (1.0f / HDIM);
  float sq = 0.0f;
#pragma unroll
  for (int j = 0; j < 8; j++) { float d = v[j] - mu; sq += d * d; }
#pragma unroll
  for (int off = 32; off; off >>= 1) sq += __shfl_xor(sq, off);
  float rs = rsqrtf(sq * (1.0f / HDIM) + 1e-5f);
  const float* xin = Xin + (long)row * HDIM + c0;
  float* xout = Xout + (long)row * HDIM + c0;
  u16 hb[8];
#pragma unroll
  for (int j = 0; j < 8; j++) {
    int c = c0 + j;
    float y = xin[j] + (v[j] - mu) * rs * gamma[c] + beta[c];
    xout[j] = y;
    hb[j] = f2b(y);
  }
  uint4 pk;
  pk.x = hb[0] | ((unsigned)hb[1] << 16);
  pk.y = hb[2] | ((unsigned)hb[3] << 16);
  pk.z = hb[4] | ((unsigned)hb[5] << 16);
  pk.w = hb[6] | ((unsigned)hb[7] << 16);
  *(uint4*)(Xb + (long)row * HDIM + c0) = pk;
}

// ---------------- launch ----------------
extern "C" void kernel_launch(void* const* d_in, const int* in_sizes, int n_in,
                              void* d_out, int out_size, void* d_ws, size_t ws_size,
                              hipStream_t stream) {
  const int*   src   = (const int*)d_in[0];
  const int*   mask  = (const int*)d_in[1];
  const float* emb   = (const float*)d_in[2];
  const float* Wq    = (const float*)d_in[3];
  const float* bq    = (const float*)d_in[4];
  const float* Wk    = (const float*)d_in[5];
  const float* bk    = (const float*)d_in[6];
  const float* Wv    = (const float*)d_in[7];
  const float* bv    = (const float*)d_in[8];
  const float* Wo    = (const float*)d_in[9];
  const float* bo    = (const float*)d_in[10];
  const float* gamma = (const float*)d_in[11];
  const float* beta  = (const float*)d_in[12];
  const float* W1    = (const float*)d_in[13];
  const float* b1    = (const float*)d_in[14];
  const float* W2    = (const float*)d_in[15];
  const float* b2    = (const float*)d_in[16];

  char* ws = (char*)d_ws;
  float* X     = (float*)(ws);                     // 0..8MB   fp32 residual
  u16*   Xb    = (u16*)(ws + (8ll << 20));         // 8..12MB  bf16 mirror
  u16*   QKVb  = (u16*)(ws + (12ll << 20));        // 12..24MB fused QKV bf16
  u16*   Mb    = (u16*)(ws + (12ll << 20));        // 12..28MB FFN mid (reuses QKV+AV)
  u16*   AVb   = (u16*)(ws + (24ll << 20));        // 24..28MB attn out bf16
  float* T     = (float*)(ws + (28ll << 20));      // 28..36MB fp32 sublayer output
  float* Lpart = (float*)(ws + (50ll << 20) + (512ll << 10)); // 512KB attn lsum partials
  u16*   Vtb   = (u16*)(ws + (51ll << 20));        // 4MB V^T [b][h][d][S]
  u64*   maskbits = (u64*)(ws + (55ll << 20));     // 512B per-tile mask bitmasks
  u16*   OpartB   = (u16*)(ws + (56ll << 20));     // 56..73MB attn bf16 O partials
  u16*   Wqkvt = (u16*)(ws + (96ll << 20));        // 96..105MB  [L][1536][512]
  u16*   Wot   = (u16*)(ws + (105ll << 20));       // 105..108MB [L][512][512]
  u16*   W1t   = (u16*)(ws + (108ll << 20));       // 108..120MB [L][2048][512]
  u16*   W2t   = (u16*)(ws + (120ll << 20));       // 120..132MB [L][512][2048]
  float* bqkv  = (float*)(ws + (132ll << 20));     // 36KB [L][1536]

  embed_pe<<<dim3(TOKENS), dim3(64), 0, stream>>>(src, emb, X, Xb);
  maskprep<<<dim3(1), dim3(64), 0, stream>>>(mask, maskbits);
  prep_weights<<<dim3(769, NLAYER), 256, 0, stream>>>(
      Wq, Wk, Wv, Wo, W1, W2, bq, bk, bv, Wqkvt, Wot, W1t, W2t, bqkv);

  for (int i = 0; i < NLAYER; i++) {
    gemm_tn<128, 128, false, false, true><<<dim3(QSTR / 128, TOKENS / 128), 256, 0, stream>>>(
        Xb, Wqkvt + (long)i * QSTR * HDIM, bqkv + i * QSTR, nullptr, QKVb,
        TOKENS, QSTR, HDIM);

    vtranspose<<<dim3(SEQ / 64, BATCH * NHEAD), 256, 0, stream>>>(QKVb, Vtb);

    attention<<<dim3(1024), 256, 0, stream>>>(QKVb, Vtb, maskbits, OpartB, Lpart);

    attn_merge<<<dim3(256), 256, 0, stream>>>(OpartB, Lpart, AVb);

    gemm_tn<64, 64, false, true, false><<<dim3(HDIM / 64, TOKENS / 64), 256, 0, stream>>>(
        AVb, Wot + (long)i * HDIM * HDIM, bo + i * HDIM, T, nullptr,
        TOKENS, HDIM, HDIM);

    ln_residual<<<dim3(TOKENS / 4), 256, 0, stream>>>(X, T, gamma + i * HDIM,
                                                      beta + i * HDIM, X, Xb);

    gemm_tn<128, 128, true, false, true><<<dim3(FFND / 128, TOKENS / 128), 256, 0, stream>>>(
        Xb, W1t + (long)i * HDIM * FFND, b1 + (long)i * FFND, nullptr, Mb,
        TOKENS, FFND, HDIM);

    gemm_tn<64, 64, false, true, false><<<dim3(HDIM / 64, TOKENS / 64), 256, 0, stream>>>(
        Mb, W2t + (long)i * FFND * HDIM, b2 + i * HDIM, T, nullptr,
        TOKENS, HDIM, FFND);

    ln_residual<<<dim3(TOKENS / 4), 256, 0, stream>>>(X, T, gamma + i * HDIM,
                                                      beta + i * HDIM, X, Xb);
  }

  hipMemcpyAsync(d_out, X, (size_t)TOKENS * HDIM * sizeof(float),
                 hipMemcpyDeviceToDevice, stream);
}

// Round 8
// 902.267 us; speedup vs baseline: 1.0636x; 1.0154x over previous
//
#include <hip/hip_runtime.h>
#include <math.h>

#define HDIM 512
#define NHEAD 8
#define NLAYER 6
#define SEQ 2048
#define BATCH 2
#define DHEAD 64
#define TOKENS (BATCH*SEQ)
#define FFND (4*HDIM)
#define QSTR 1536   // fused QKV row stride

typedef unsigned short u16;
typedef unsigned long long u64;
typedef __attribute__((ext_vector_type(8))) short short8;
typedef __attribute__((ext_vector_type(4))) float f32x4;

__device__ __forceinline__ u16 f2b(float f) {
  unsigned u = __float_as_uint(f);
  u += 0x7FFFu + ((u >> 16) & 1u);
  return (u16)(u >> 16);
}

__device__ __forceinline__ float b2f(u16 u) {
  return __uint_as_float((unsigned)u << 16);
}

__device__ __forceinline__ unsigned cvtpk_bf16(float lo, float hi) {
  unsigned r;
  asm("v_cvt_pk_bf16_f32 %0, %1, %2" : "=v"(r) : "v"(lo), "v"(hi));
  return r;
}

__device__ __forceinline__ void gload_lds16(const u16* g, u16* l) {
  __builtin_amdgcn_global_load_lds((const __attribute__((address_space(1))) void*)g,
                                   (__attribute__((address_space(3))) void*)l, 16, 0, 0);
}

// ---------------- embed + positional encoding ----------------
__global__ void embed_pe(const int* __restrict__ src, const float* __restrict__ emb,
                         float* __restrict__ X, u16* __restrict__ Xb) {
  int tok = blockIdx.x;
  int lane = threadIdx.x;           // 64 threads
  int s = tok & (SEQ - 1);
  int c0 = lane * 8;
  const float* e = emb + (long)src[tok] * HDIM + c0;
  float v[8];
#pragma unroll
  for (int j = 0; j < 8; j++) {
    int c = c0 + j;
    float arg = (float)s * exp2f(-(float)(c & ~1) * 0.02595256917f);
    v[j] = e[j] + ((c & 1) ? cosf(arg) : sinf(arg));
  }
  float* xp = X + (long)tok * HDIM + c0;
#pragma unroll
  for (int j = 0; j < 8; j++) xp[j] = v[j];
  u16 hb[8];
#pragma unroll
  for (int j = 0; j < 8; j++) hb[j] = f2b(v[j]);
  uint4 pk;
  pk.x = hb[0] | ((unsigned)hb[1] << 16);
  pk.y = hb[2] | ((unsigned)hb[3] << 16);
  pk.z = hb[4] | ((unsigned)hb[5] << 16);
  pk.w = hb[6] | ((unsigned)hb[7] << 16);
  *(uint4*)(Xb + (long)tok * HDIM + c0) = pk;
}

// ---------------- mask -> per-64-key-tile bitmasks (once per net) ----------------
__global__ void maskprep(const int* __restrict__ mask, u64* __restrict__ mb) {
  int t = threadIdx.x;              // 64 threads: b = t>>5, tile = t&31
  int b = t >> 5, tile = t & 31;
  const int* m = mask + b * SEQ + tile * 64;
  u64 w = 0;
#pragma unroll
  for (int j = 0; j < 64; j++) w |= (u64)(m[j] != 0) << j;
  mb[t] = w;
}

// ---------------- ALL-layer weight prep (once): fp32 [K][N] -> bf16 [N][K] ----------------
__global__ __launch_bounds__(256) void prep_weights(
    const float* __restrict__ Wq, const float* __restrict__ Wk, const float* __restrict__ Wv,
    const float* __restrict__ Wo, const float* __restrict__ W1, const float* __restrict__ W2,
    const float* __restrict__ bq, const float* __restrict__ bk, const float* __restrict__ bv,
    u16* __restrict__ Wqkvt, u16* __restrict__ Wot, u16* __restrict__ W1t, u16* __restrict__ W2t,
    float* __restrict__ bqkv) {
  int L = blockIdx.y;
  int t = blockIdx.x;
  int tid = threadIdx.x;
  const float* Wq_ = Wq + (long)L * HDIM * HDIM;
  const float* Wk_ = Wk + (long)L * HDIM * HDIM;
  const float* Wv_ = Wv + (long)L * HDIM * HDIM;
  const float* Wo_ = Wo + (long)L * HDIM * HDIM;
  const float* W1_ = W1 + (long)L * HDIM * FFND;
  const float* W2_ = W2 + (long)L * FFND * HDIM;
  u16* Wqkvt_ = Wqkvt + (long)L * QSTR * HDIM;
  u16* Wot_   = Wot   + (long)L * HDIM * HDIM;
  u16* W1t_   = W1t   + (long)L * HDIM * FFND;
  u16* W2t_   = W2t   + (long)L * FFND * HDIM;
  if (t == 768) {
    const float* bq_ = bq + L * HDIM;
    const float* bk_ = bk + L * HDIM;
    const float* bv_ = bv + L * HDIM;
    float* bqkv_ = bqkv + L * QSTR;
    for (int i = tid; i < 1536; i += 256)
      bqkv_[i] = (i < 512) ? bq_[i] : (i < 1024) ? bk_[i - 512] : bv_[i - 1024];
    return;
  }
  const float* src; u16* dst; int K, N, kt, nt; long drow0 = 0;
  if (t < 192)      { int m = t / 64, r = t % 64; src = (m==0)?Wq_:(m==1)?Wk_:Wv_; dst = Wqkvt_; drow0 = (long)m*512; K=512;  N=512;  kt=r/8;  nt=r%8; }
  else if (t < 256) { int r = t - 192; src = Wo_; dst = Wot_; K=512;  N=512;  kt=r/8;  nt=r%8; }
  else if (t < 512) { int r = t - 256; src = W1_; dst = W1t_; K=512;  N=2048; kt=r/32; nt=r%32; }
  else              { int r = t - 512; src = W2_; dst = W2t_; K=2048; N=512;  kt=r/8;  nt=r%8; }
  __shared__ __align__(16) u16 Lt[64 * 72];
  int kl = tid >> 2;                 // local k row 0..63
#pragma unroll
  for (int rr = 0; rr < 4; rr++) {
    int cl = (tid & 3) * 4 + rr * 16;  // local n col
    float4 v = *(const float4*)(src + (long)(kt * 64 + kl) * N + nt * 64 + cl);
    Lt[(cl + 0) * 72 + kl] = f2b(v.x);
    Lt[(cl + 1) * 72 + kl] = f2b(v.y);
    Lt[(cl + 2) * 72 + kl] = f2b(v.z);
    Lt[(cl + 3) * 72 + kl] = f2b(v.w);
  }
  __syncthreads();
  int nl = tid >> 2;                 // out row (n) 0..63
  int kc = (tid & 3) * 16;           // out col chunk (k)
  u16* dp = dst + (drow0 + nt * 64 + nl) * (long)K + kt * 64 + kc;
  *(uint4*)dp       = *(const uint4*)&Lt[nl * 72 + kc];
  *(uint4*)(dp + 8) = *(const uint4*)&Lt[nl * 72 + kc + 8];
}

// ---------------- bf16 TN GEMM, double-buffered; optional fused V-transpose epilogue ----------------
// WVT (QKV GEMM only): blocks with n0>=1024 hold V in accumulators; they write
// Vtb[b][h][d][S] directly (4 consecutive tokens per lane -> packed uint2 along
// S) and skip the QKVb write.  Replaces the separate vtranspose kernel.
template <int BM, int BN, bool RELU, bool WF32, bool WB16, bool WVT>
__global__ __launch_bounds__(256) void gemm_tn(const u16* __restrict__ A,
                                               const u16* __restrict__ Bt,
                                               const float* __restrict__ bias,
                                               float* __restrict__ Cf,
                                               u16* __restrict__ Cb,
                                               u16* __restrict__ Vt,
                                               int M, int N, int K) {
  constexpr int NF = BN / 32;                 // n-frags per wave
  constexpr int MF = BM / 32;                 // m-frags per wave
  __shared__ __align__(16) u16 As[2][BM * 32];
  __shared__ __align__(16) u16 Bs[2][BN * 32];
  int tid = threadIdx.x;
  int wave = tid >> 6, lane = tid & 63;
  int ln = lane & 15, hi = lane >> 4;
  int wm = wave >> 1, wn = wave & 1;
  int m0 = blockIdx.y * BM, n0 = blockIdx.x * BN;

  f32x4 acc[MF][NF] = {};

  int srow = lane >> 2;        // 0..15
  int skc  = (lane & 3) * 8;   // k-chunk within 32

  auto issue = [&](int kt, int buf) {
    int k0 = kt * 32;
#pragma unroll
    for (int j = 0; j < BM / 64; j++) {
      int row = (wave * (BM / 64) + j) * 16 + srow;
      gload_lds16(A + (long)(m0 + row) * K + k0 + skc, &As[buf][row * 32 + skc]);
    }
#pragma unroll
    for (int j = 0; j < BN / 64; j++) {
      int row = (wave * (BN / 64) + j) * 16 + srow;
      gload_lds16(Bt + (long)(n0 + row) * K + k0 + skc, &Bs[buf][row * 32 + skc]);
    }
  };

  int NT = K / 32;
  issue(0, 0);
  __syncthreads();
  for (int kt = 0; kt < NT; kt++) {
    int buf = kt & 1;
    if (kt + 1 < NT) issue(kt + 1, buf ^ 1);
    short8 af[MF], bf[NF];
#pragma unroll
    for (int mt = 0; mt < MF; mt++)
      af[mt] = *(const short8*)&As[buf][(wm * (BM / 2) + mt * 16 + ln) * 32 + 8 * hi];
#pragma unroll
    for (int nt = 0; nt < NF; nt++)
      bf[nt] = *(const short8*)&Bs[buf][(wn * (BN / 2) + nt * 16 + ln) * 32 + 8 * hi];
#pragma unroll
    for (int mt = 0; mt < MF; mt++)
#pragma unroll
      for (int nt = 0; nt < NF; nt++)
        acc[mt][nt] = __builtin_amdgcn_mfma_f32_16x16x32_bf16(af[mt], bf[nt], acc[mt][nt], 0, 0, 0);
    __syncthreads();
  }

  if (WVT && n0 >= 1024) {
    // V region: write transposed Vtb[b][h][d][S] directly; skip QKVb write.
    int bb = m0 >> 11;                        // batch (BM=128 tiles never cross SEQ)
    int sbase = m0 & (SEQ - 1);
#pragma unroll
    for (int mt = 0; mt < MF; mt++) {
      int s0 = sbase + wm * (BM / 2) + mt * 16 + hi * 4;   // 4 consecutive tokens
#pragma unroll
      for (int nt = 0; nt < NF; nt++) {
        int col = n0 + wn * (BN / 2) + nt * 16 + ln;
        int gd = col - 1024;
        float bcol = bias[col];
        uint2 val;
        val.x = cvtpk_bf16(acc[mt][nt][0] + bcol, acc[mt][nt][1] + bcol);
        val.y = cvtpk_bf16(acc[mt][nt][2] + bcol, acc[mt][nt][3] + bcol);
        *(uint2*)(Vt + ((long)(bb * NHEAD + (gd >> 6)) * DHEAD + (gd & 63)) * SEQ + s0) = val;
      }
    }
    return;
  }

#pragma unroll
  for (int mt = 0; mt < MF; mt++)
#pragma unroll
    for (int nt = 0; nt < NF; nt++)
#pragma unroll
      for (int r = 0; r < 4; r++) {
        int row = m0 + wm * (BM / 2) + mt * 16 + hi * 4 + r;
        int col = n0 + wn * (BN / 2) + nt * 16 + ln;
        float v = acc[mt][nt][r] + bias[col];
        if (RELU) v = fmaxf(v, 0.0f);
        if (WF32) Cf[(long)row * N + col] = v;
        if (WB16) Cb[(long)row * N + col] = f2b(v);
      }
}

// ---------------- flash attention, QBLK=128 (32 q/wave), key-split-4, bf16 partials ----------------
__global__ __launch_bounds__(256) void attention(const u16* __restrict__ QKV,
                                                 const u16* __restrict__ Vtb,
                                                 const u64* __restrict__ maskb,
                                                 u16* __restrict__ Opart,
                                                 float* __restrict__ Lpart) {
  __shared__ __align__(16) u16 Ks[2][64 * 64];  // [buf][slot][d]  (chunk-swizzled)
  __shared__ __align__(16) u16 Vs[2][64 * 64];  // [buf][d][key]   (chunk-swizzled)
  __shared__ u64 Msk[SEQ / 64];
  int tid = threadIdx.x, w = tid >> 6, lane = tid & 63;
  int ln = lane & 15, hi = lane >> 4;
  int h0 = hi & 1, h1 = hi >> 1, ln7 = ln & 7;
  int lin = blockIdx.x;                        // 1024 blocks, 1-D
  int lid = (lin & 7) * 128 + (lin >> 3);      // bijective XCD-contiguous swizzle
  int bh = lid >> 6, rem = lid & 63;
  int qt = rem >> 2, kz = rem & 3;
  int b = bh >> 3, h = bh & 7;
  int q0 = qt * 128 + w * 32;                  // wave's 32 q-rows
  const u16* qbase = QKV + (long)b * SEQ * QSTR + h * DHEAD;
  const u16* kbase = qbase + 512;
  const u16* vtbase = Vtb + (long)bh * DHEAD * SEQ;

  // Q fragments (B-operand): qf[qg][ks], lane holds Q[q0+qg*16+ln][ks*32+8*hi..]
  short8 qf[2][2];
#pragma unroll
  for (int qg = 0; qg < 2; qg++)
#pragma unroll
    for (int ks = 0; ks < 2; ks++)
      qf[qg][ks] = *(const short8*)(qbase + (long)(q0 + qg * 16 + ln) * QSTR + ks * 32 + 8 * hi);

  u64 mw0 = 0;
  if (tid < SEQ / 64) mw0 = maskb[b * (SEQ / 64) + tid];

  // staging geometry: 256 thr x 16B x 2 issues = 8KB per tile per buffer
  int sr0 = tid >> 3, sc = tid & 7;
  const u16 *kp0, *kp1, *vp0, *vp1;
  {
    int r1 = sr0 + 32;
    int key0 = (sr0 & 7) | ((sr0 & 0x18) << 1) | ((sr0 & 0x20) >> 2);
    int key1 = (r1 & 7) | ((r1 & 0x18) << 1) | ((r1 & 0x20) >> 2);
    kp0 = kbase + (long)key0 * QSTR + (sc ^ (sr0 & 7)) * 8;
    kp1 = kbase + (long)key1 * QSTR + (sc ^ (r1 & 7)) * 8;
    vp0 = vtbase + (long)sr0 * SEQ + (sc ^ (sr0 & 7)) * 8;
    vp1 = vtbase + (long)r1 * SEQ + (sc ^ (r1 & 7)) * 8;
  }
  int d0 = sr0 * 64 + sc * 8, d1 = d0 + 2048;

  auto issue = [&](int t, int buf) {
    long ko = (long)t * (64 * QSTR);
    int vo = t * 64;
    gload_lds16(kp0 + ko, &Ks[buf][d0]);
    gload_lds16(kp1 + ko, &Ks[buf][d1]);
    gload_lds16(vp0 + vo, &Vs[buf][d0]);
    gload_lds16(vp1 + vo, &Vs[buf][d1]);
  };

  f32x4 o[2][4] = {};
  float lsum[2] = {0.0f, 0.0f};
  const int t0 = kz * 8;
  const int NTL = 8;                           // tiles per block (key-split quarter)

  issue(t0, 0);
  issue(t0 + 1, 1);
  if (tid < SEQ / 64) Msk[tid] = mw0;
  asm volatile("s_waitcnt vmcnt(4)" ::: "memory");   // tile t0 (+q,+mask) done; t0+1 in flight
  __builtin_amdgcn_sched_barrier(0);
  __builtin_amdgcn_s_barrier();
  __builtin_amdgcn_sched_barrier(0);

  for (int ti = 0; ti < NTL; ti++) {
    int buf = ti & 1;
    u64 mw = Msk[t0 + ti];

    // S^T: s[qg][kb][r] = S[q=q0+qg*16+ln][slot = kb*16 + hi*4 + r]
    f32x4 s[2][4] = {};
    __builtin_amdgcn_s_setprio(1);
#pragma unroll
    for (int ks = 0; ks < 2; ks++)
#pragma unroll
      for (int kb = 0; kb < 4; kb++) {
        short8 kf = *(const short8*)&Ks[buf][(kb * 16 + ln) * 64 + (((ks << 2) + hi) ^ ln7) * 8];
        s[0][kb] = __builtin_amdgcn_mfma_f32_16x16x32_bf16(kf, qf[0][ks], s[0][kb], 0, 0, 0);
        s[1][kb] = __builtin_amdgcn_mfma_f32_16x16x32_bf16(kf, qf[1][ks], s[1][kb], 0, 0, 0);
      }
    __builtin_amdgcn_s_setprio(0);

    // softmax numerator + pack to bf16 pairs (s freed as D is built)
    unsigned D[2][4][2];
    if (mw == 0xFFFFFFFFFFFFFFFFull) {
#pragma unroll
      for (int qg = 0; qg < 2; qg++)
#pragma unroll
        for (int kb = 0; kb < 4; kb++) {
          float p[4];
#pragma unroll
          for (int r = 0; r < 4; r++) {
            float pv = __expf(s[qg][kb][r] * 0.125f);
            lsum[qg] += pv;
            p[r] = pv;
          }
          D[qg][kb][0] = cvtpk_bf16(p[0], p[1]);
          D[qg][kb][1] = cvtpk_bf16(p[2], p[3]);
        }
    } else {
      // lane's key bit positions: 16*h1 + 4*h0 + {0,32,8,40}[kb] + r (q-indep)
      unsigned shb = h1 * 16 + h0 * 4;
      u64 mws = mw >> shb;
      unsigned nib[4] = { (unsigned)mws & 0xFu, (unsigned)(mws >> 32) & 0xFu,
                          (unsigned)(mws >> 8) & 0xFu, (unsigned)(mws >> 40) & 0xFu };
#pragma unroll
      for (int qg = 0; qg < 2; qg++)
#pragma unroll
        for (int kb = 0; kb < 4; kb++) {
          float p[4];
#pragma unroll
          for (int r = 0; r < 4; r++) {
            float pv = __expf(s[qg][kb][r] * 0.125f);
            pv = ((nib[kb] >> r) & 1u) ? pv : 0.0f;
            lsum[qg] += pv;
            p[r] = pv;
          }
          D[qg][kb][0] = cvtpk_bf16(p[0], p[1]);
          D[qg][kb][1] = cvtpk_bf16(p[2], p[3]);
        }
    }

    // O^T += V^T @ P^T : pb assembled per-ks (keeps register peak low);
    // each vf read feeds both q-groups.
    __builtin_amdgcn_s_setprio(1);
#pragma unroll
    for (int ks = 0; ks < 2; ks++) {
      short8 pb[2];
#pragma unroll
      for (int qg = 0; qg < 2; qg++) {
        unsigned own0 = h0 ? D[qg][2 + ks][0] : D[qg][ks][0];
        unsigned own1 = h0 ? D[qg][2 + ks][1] : D[qg][ks][1];
        unsigned snd0 = h0 ? D[qg][ks][0] : D[qg][2 + ks][0];
        unsigned snd1 = h0 ? D[qg][ks][1] : D[qg][2 + ks][1];
        unsigned rc0 = (unsigned)__shfl_xor((int)snd0, 16);
        unsigned rc1 = (unsigned)__shfl_xor((int)snd1, 16);
        union { unsigned u[4]; short8 v; } pu;
        pu.u[0] = h0 ? rc0 : own0;
        pu.u[1] = h0 ? rc1 : own1;
        pu.u[2] = h0 ? own0 : rc0;
        pu.u[3] = h0 ? own1 : rc1;
        pb[qg] = pu.v;
      }
#pragma unroll
      for (int mb = 0; mb < 4; mb++) {
        short8 vf = *(const short8*)&Vs[buf][(mb * 16 + ln) * 64 + (((ks << 2) + hi) ^ ln7) * 8];
        o[0][mb] = __builtin_amdgcn_mfma_f32_16x16x32_bf16(vf, pb[0], o[0][mb], 0, 0, 0);
        o[1][mb] = __builtin_amdgcn_mfma_f32_16x16x32_bf16(vf, pb[1], o[1][mb], 0, 0, 0);
      }
    }
    __builtin_amdgcn_s_setprio(0);

    // barrier #1: all waves done READING buf (own ds reads drained first)
    asm volatile("s_waitcnt lgkmcnt(0)" ::: "memory");
    __builtin_amdgcn_sched_barrier(0);
    __builtin_amdgcn_s_barrier();
    __builtin_amdgcn_sched_barrier(0);
    // prefetch ti+2 into buf; wait only until ti+1's loads are home
    if (ti + 2 < NTL) {
      issue(t0 + ti + 2, buf);
      asm volatile("s_waitcnt vmcnt(4)" ::: "memory");
    } else {
      asm volatile("s_waitcnt vmcnt(0)" ::: "memory");
    }
    __builtin_amdgcn_sched_barrier(0);
    __builtin_amdgcn_s_barrier();   // barrier #2: tile ti+1 staged for everyone
    __builtin_amdgcn_sched_barrier(0);
  }

  // partial row-sums: combine over hi groups -> every lane has row total
#pragma unroll
  for (int qg = 0; qg < 2; qg++) {
    lsum[qg] += __shfl_xor(lsum[qg], 16);
    lsum[qg] += __shfl_xor(lsum[qg], 32);
  }

  // bf16 partial O: block-contiguous [128 q][64 d]
  u16* OpB = Opart + (long)lid * 8192 + w * 2048;
#pragma unroll
  for (int qg = 0; qg < 2; qg++)
#pragma unroll
    for (int mb = 0; mb < 4; mb++) {
      uint2 val;
      val.x = cvtpk_bf16(o[qg][mb][0], o[qg][mb][1]);
      val.y = cvtpk_bf16(o[qg][mb][2], o[qg][mb][3]);
      *(uint2*)&OpB[(qg * 16 + ln) * 64 + mb * 16 + hi * 4] = val;
    }
  if (hi == 0) {
    Lpart[(long)lid * 128 + w * 32 + ln]      = lsum[0];
    Lpart[(long)lid * 128 + w * 32 + 16 + ln] = lsum[1];
  }
}

// ---------------- merge key-split-4 bf16 partials -> bf16 AVb ----------------
__global__ __launch_bounds__(256) void attn_merge(const u16* __restrict__ Op,
                                                  const float* __restrict__ Lp,
                                                  u16* __restrict__ Og) {
  int lin = blockIdx.x;                       // 256 blocks
  int mlid = (lin & 7) * 32 + (lin >> 3);     // XCD-matched swizzle (same L2 as producer)
  int bh = mlid >> 4, qt = mlid & 15;
  int b = bh >> 3, h = bh & 7;
  int tid = threadIdx.x;
  __shared__ float Ls[128];
  long lbase = (long)mlid * 4 * 128;          // producer lids = mlid*4 + kz
  if (tid < 128) {
    float l = Lp[lbase + tid] + Lp[lbase + 128 + tid] +
              Lp[lbase + 256 + tid] + Lp[lbase + 384 + tid];
    Ls[tid] = 1.0f / l;
  }
  __syncthreads();
  const u16* P0 = Op + (long)mlid * 4 * 8192;
  u16* obase = Og + (long)b * SEQ * HDIM + (long)qt * 128 * HDIM + h * DHEAD;
#pragma unroll
  for (int j = 0; j < 8; j++) {
    int flat = j * 1024 + tid * 4;
    int row = flat >> 6, c = flat & 63;
    float a0 = 0.0f, a1 = 0.0f, a2 = 0.0f, a3 = 0.0f;
#pragma unroll
    for (int z = 0; z < 4; z++) {
      uint2 pv = *(const uint2*)&P0[z * 8192 + flat];
      a0 += b2f((u16)pv.x);  a1 += b2f((u16)(pv.x >> 16));
      a2 += b2f((u16)pv.y);  a3 += b2f((u16)(pv.y >> 16));
    }
    float rl = Ls[row];
    uint2 val;
    val.x = cvtpk_bf16(a0 * rl, a1 * rl);
    val.y = cvtpk_bf16(a2 * rl, a3 * rl);
    *(uint2*)(obase + (long)row * HDIM + c) = val;
  }
}

// ---------------- residual + LayerNorm over single fp32 sublayer output ----------------
__global__ __launch_bounds__(256) void ln_residual(const float* __restrict__ Xin,
                                                   const float* __restrict__ T0,
                                                   const float* __restrict__ gamma,
                                                   const float* __restrict__ beta,
                                                   float* __restrict__ Xout,
                                                   u16* __restrict__ Xb) {
  int tid = threadIdx.x, w = tid >> 6, lane = tid & 63;
  int row = blockIdx.x * 4 + w;
  const float* t0 = T0 + (long)row * HDIM;
  int c0 = lane * 8;
  float v[8];
  {
    float4 a0 = *(const float4*)(t0 + c0);
    float4 b0 = *(const float4*)(t0 + c0 + 4);
    v[0] = a0.x; v[1] = a0.y; v[2] = a0.z; v[3] = a0.w;
    v[4] = b0.x; v[5] = b0.y; v[6] = b0.z; v[7] = b0.w;
  }
  float sum = 0.0f;
#pragma unroll
  for (int j = 0; j < 8; j++) sum += v[j];
#pragma unroll
  for (int off = 32; off; off >>= 1) sum += __shfl_xor(sum, off);
  float mu = sum * (1.0f / HDIM);
  float sq = 0.0f;
#pragma unroll
  for (int j = 0; j < 8; j++) { float d = v[j] - mu; sq += d * d; }
#pragma unroll
  for (int off = 32; off; off >>= 1) sq += __shfl_xor(sq, off);
  float rs = rsqrtf(sq * (1.0f / HDIM) + 1e-5f);
  const float* xin = Xin + (long)row * HDIM + c0;
  float* xout = Xout + (long)row * HDIM + c0;
  u16 hb[8];
#pragma unroll
  for (int j = 0; j < 8; j++) {
    int c = c0 + j;
    float y = xin[j] + (v[j] - mu) * rs * gamma[c] + beta[c];
    xout[j] = y;
    hb[j] = f2b(y);
  }
  uint4 pk;
  pk.x = hb[0] | ((unsigned)hb[1] << 16);
  pk.y = hb[2] | ((unsigned)hb[3] << 16);
  pk.z = hb[4] | ((unsigned)hb[5] << 16);
  pk.w = hb[6] | ((unsigned)hb[7] << 16);
  *(uint4*)(Xb + (long)row * HDIM + c0) = pk;
}

// ---------------- launch ----------------
extern "C" void kernel_launch(void* const* d_in, const int* in_sizes, int n_in,
                              void* d_out, int out_size, void* d_ws, size_t ws_size,
                              hipStream_t stream) {
  const int*   src   = (const int*)d_in[0];
  const int*   mask  = (const int*)d_in[1];
  const float* emb   = (const float*)d_in[2];
  const float* Wq    = (const float*)d_in[3];
  const float* bq    = (const float*)d_in[4];
  const float* Wk    = (const float*)d_in[5];
  const float* bk    = (const float*)d_in[6];
  const float* Wv    = (const float*)d_in[7];
  const float* bv    = (const float*)d_in[8];
  const float* Wo    = (const float*)d_in[9];
  const float* bo    = (const float*)d_in[10];
  const float* gamma = (const float*)d_in[11];
  const float* beta  = (const float*)d_in[12];
  const float* W1    = (const float*)d_in[13];
  const float* b1    = (const float*)d_in[14];
  const float* W2    = (const float*)d_in[15];
  const float* b2    = (const float*)d_in[16];

  char* ws = (char*)d_ws;
  float* X     = (float*)(ws);                     // 0..8MB   fp32 residual
  u16*   Xb    = (u16*)(ws + (8ll << 20));         // 8..12MB  bf16 mirror
  u16*   QKVb  = (u16*)(ws + (12ll << 20));        // 12..24MB fused QKV bf16 (V region unused)
  u16*   Mb    = (u16*)(ws + (12ll << 20));        // 12..28MB FFN mid (reuses QKV+AV)
  u16*   AVb   = (u16*)(ws + (24ll << 20));        // 24..28MB attn out bf16
  float* T     = (float*)(ws + (28ll << 20));      // 28..36MB fp32 sublayer output
  float* Lpart = (float*)(ws + (50ll << 20) + (512ll << 10)); // 512KB attn lsum partials
  u16*   Vtb   = (u16*)(ws + (51ll << 20));        // 4MB V^T [b][h][d][S]
  u64*   maskbits = (u64*)(ws + (55ll << 20));     // 512B per-tile mask bitmasks
  u16*   OpartB   = (u16*)(ws + (56ll << 20));     // 56..73MB attn bf16 O partials
  u16*   Wqkvt = (u16*)(ws + (96ll << 20));        // 96..105MB  [L][1536][512]
  u16*   Wot   = (u16*)(ws + (105ll << 20));       // 105..108MB [L][512][512]
  u16*   W1t   = (u16*)(ws + (108ll << 20));       // 108..120MB [L][2048][512]
  u16*   W2t   = (u16*)(ws + (120ll << 20));       // 120..132MB [L][512][2048]
  float* bqkv  = (float*)(ws + (132ll << 20));     // 36KB [L][1536]

  embed_pe<<<dim3(TOKENS), dim3(64), 0, stream>>>(src, emb, X, Xb);
  maskprep<<<dim3(1), dim3(64), 0, stream>>>(mask, maskbits);
  prep_weights<<<dim3(769, NLAYER), 256, 0, stream>>>(
      Wq, Wk, Wv, Wo, W1, W2, bq, bk, bv, Wqkvt, Wot, W1t, W2t, bqkv);

  for (int i = 0; i < NLAYER; i++) {
    // QKV GEMM with fused V-transpose epilogue (V blocks write Vtb directly)
    gemm_tn<128, 128, false, false, true, true><<<dim3(QSTR / 128, TOKENS / 128), 256, 0, stream>>>(
        Xb, Wqkvt + (long)i * QSTR * HDIM, bqkv + i * QSTR, nullptr, QKVb, Vtb,
        TOKENS, QSTR, HDIM);

    attention<<<dim3(1024), 256, 0, stream>>>(QKVb, Vtb, maskbits, OpartB, Lpart);

    attn_merge<<<dim3(256), 256, 0, stream>>>(OpartB, Lpart, AVb);

    gemm_tn<64, 64, false, true, false, false><<<dim3(HDIM / 64, TOKENS / 64), 256, 0, stream>>>(
        AVb, Wot + (long)i * HDIM * HDIM, bo + i * HDIM, T, nullptr, nullptr,
        TOKENS, HDIM, HDIM);

    ln_residual<<<dim3(TOKENS / 4), 256, 0, stream>>>(X, T, gamma + i * HDIM,
                                                      beta + i * HDIM, X, Xb);

    gemm_tn<128, 128, true, false, true, false><<<dim3(FFND / 128, TOKENS / 128), 256, 0, stream>>>(
        Xb, W1t + (long)i * HDIM * FFND, b1 + (long)i * FFND, nullptr, Mb, nullptr,
        TOKENS, FFND, HDIM);

    gemm_tn<64, 64, false, true, false, false><<<dim3(HDIM / 64, TOKENS / 64), 256, 0, stream>>>(
        Mb, W2t + (long)i * FFND * HDIM, b2 + i * HDIM, T, nullptr, nullptr,
        TOKENS, HDIM, FFND);

    // final layer writes the fp32 residual straight to d_out (no trailing memcpy)
    ln_residual<<<dim3(TOKENS / 4), 256, 0, stream>>>(
        X, T, gamma + i * HDIM, beta + i * HDIM,
        (i == NLAYER - 1) ? (float*)d_out : X, Xb);
  }
}